// Round 4
// baseline (1969.470 us; speedup 1.0000x reference)
//
#include <hip/hip_runtime.h>
#include <hip/hip_bf16.h>
#include <math.h>

#define BB 16
#define TT 256
#define DD 512
#define EE 512
#define VV 32000
#define G4 2048   // 4*D

typedef __attribute__((ext_vector_type(4))) float f32x4;
typedef __attribute__((ext_vector_type(8))) short bf16x8;

union frag_u { unsigned long long u[2]; bf16x8 v; };

#define SENTMASK 0x4000400040004000ULL   // bit14 of each bf16: set in 0xFFFF sentinel, clear for |x|<2

__device__ __forceinline__ unsigned short f2bf(float x) {
    unsigned u = __float_as_uint(x);
    unsigned r = (u + 0x7FFFu + ((u >> 16) & 1u)) >> 16;
    return (unsigned short)r;
}

__device__ __forceinline__ float sigmoidf_(float x) { return 1.0f / (1.0f + expf(-x)); }

// ---------------- embedding gather -> bf16 (padding_idx=0 -> zero row) ----------------
__global__ __launch_bounds__(256) void k_gather(const int* __restrict__ tok,
        const float* __restrict__ embed, unsigned short* __restrict__ Xb) {
    int m = blockIdx.x;
    int tk = tok[m];
    const float* src = embed + (size_t)tk * DD;
    int i = threadIdx.x * 2;
    float vx = 0.f, vy = 0.f;
    if (tk != 0) { float2 v = *(const float2*)&src[i]; vx = v.x; vy = v.y; }
    ushort2 o; o.x = f2bf(vx); o.y = f2bf(vy);
    *(ushort2*)&Xb[(size_t)m * DD + i] = o;
}

// ---------------- generic fp32 -> bf16 convert (contiguous) ----------------
__global__ __launch_bounds__(256) void k_cvt(const float* __restrict__ in,
        unsigned short* __restrict__ out, int n4) {
    int i = blockIdx.x * 256 + threadIdx.x;
    if (i >= n4) return;
    float4 v = ((const float4*)in)[i];
    ushort4 o; o.x = f2bf(v.x); o.y = f2bf(v.y); o.z = f2bf(v.z); o.w = f2bf(v.w);
    ((ushort4*)out)[i] = o;
}

// ---------------- W_ih0[:, 0:512] -> packed bf16 [2048,512] ----------------
__global__ __launch_bounds__(256) void k_cvt_wih0x(const float* __restrict__ Wih0,
        unsigned short* __restrict__ out) {
    int i = blockIdx.x * 256 + threadIdx.x;
    int j = i >> 7;
    int k4 = (i & 127) << 2;
    float4 v = *(const float4*)&Wih0[(size_t)j * (EE + DD) + k4];
    ushort4 o; o.x = f2bf(v.x); o.y = f2bf(v.y); o.z = f2bf(v.z); o.w = f2bf(v.w);
    *(ushort4*)&out[(size_t)j * DD + k4] = o;
}

// ---------------- enc_term[b,j] = b_ih0[j]+b_hh0[j] + enc[b,:] . W_ih0[j, 512:1024] ----------------
__global__ __launch_bounds__(256) void k_encterm(const float* __restrict__ enc,
        const float* __restrict__ Wih0, const float* __restrict__ bih0,
        const float* __restrict__ bhh0, float* __restrict__ et) {
    int b = blockIdx.x >> 3, jc = blockIdx.x & 7;
    int tid = threadIdx.x, lane = tid & 63, w = tid >> 6;
    __shared__ float es[EE];
    if (tid < EE / 4) *(float4*)&es[tid * 4] = *(const float4*)&enc[b * EE + tid * 4];
    __syncthreads();
    float4 e0 = *(const float4*)&es[lane * 4];
    float4 e1 = *(const float4*)&es[256 + lane * 4];
    for (int o = 0; o < 64; ++o) {
        int j = jc * 256 + w * 64 + o;
        const float4* Wr = (const float4*)&Wih0[(size_t)j * (EE + DD) + DD];
        float4 w0 = Wr[lane], w1 = Wr[64 + lane];
        float s = w0.x*e0.x + w0.y*e0.y + w0.z*e0.z + w0.w*e0.w
                + w1.x*e1.x + w1.y*e1.y + w1.z*e1.z + w1.w*e1.w;
        #pragma unroll
        for (int off = 32; off; off >>= 1) s += __shfl_xor(s, off);
        if (lane == 0) et[b * G4 + j] = s + bih0[j] + bhh0[j];
    }
}

// ---------------- bf16 MFMA GEMM, C[M,N] = A[M,K] @ B[N,K]^T  (m97 structure) ----------------
template<int EPI>
__global__ __launch_bounds__(256) void k_gemm_bt(
        const unsigned short* __restrict__ A, const unsigned short* __restrict__ Bm,
        float* __restrict__ C, const float* __restrict__ extra,
        int M, int N, int K) {
    __shared__ __align__(16) unsigned short Alds[128 * 32];
    __shared__ __align__(16) unsigned short Blds[128 * 32];
    int tid = threadIdx.x, lane = tid & 63, w = tid >> 6;
    int wr = w >> 1, wc = w & 1;
    int m0 = blockIdx.x * 128, n0 = blockIdx.y * 128;
    f32x4 acc[4][4];
    #pragma unroll
    for (int i = 0; i < 4; i++)
        #pragma unroll
        for (int j = 0; j < 4; j++) acc[i][j] = (f32x4)0.f;

    const char* Abase = (const char*)A;
    const char* Bbase = (const char*)Bm;
    for (int ks = 0; ks < K; ks += 32) {
        #pragma unroll
        for (int c = 0; c < 2; ++c) {
            int f = (tid + c * 256) * 16;
            int row = f >> 6;
            int inb = f & 63;
            const char* gA = Abase + (((size_t)(m0 + row) * K + ks) * 2 + inb);
            __builtin_amdgcn_global_load_lds(
                (const __attribute__((address_space(1))) void*)gA,
                (__attribute__((address_space(3))) void*)((char*)Alds + f), 16, 0, 0);
            const char* gB = Bbase + (((size_t)(n0 + row) * K + ks) * 2 + inb);
            __builtin_amdgcn_global_load_lds(
                (const __attribute__((address_space(1))) void*)gB,
                (__attribute__((address_space(3))) void*)((char*)Blds + f), 16, 0, 0);
        }
        __syncthreads();
        bf16x8 af[4], bfr[4];
        int r = lane & 15, ko = (lane >> 4) * 8;
        #pragma unroll
        for (int mi = 0; mi < 4; ++mi)
            af[mi] = *(const bf16x8*)&Alds[(wr * 64 + mi * 16 + r) * 32 + ko];
        #pragma unroll
        for (int ni = 0; ni < 4; ++ni)
            bfr[ni] = *(const bf16x8*)&Blds[(wc * 64 + ni * 16 + r) * 32 + ko];
        #pragma unroll
        for (int mi = 0; mi < 4; ++mi)
            #pragma unroll
            for (int ni = 0; ni < 4; ++ni)
                acc[mi][ni] = __builtin_amdgcn_mfma_f32_16x16x32_bf16(af[mi], bfr[ni], acc[mi][ni], 0, 0, 0);
        __syncthreads();
    }
    int cr = (lane >> 4) * 4, cc = lane & 15;
    #pragma unroll
    for (int mi = 0; mi < 4; ++mi) {
        #pragma unroll
        for (int ni = 0; ni < 4; ++ni) {
            int col = n0 + wc * 64 + ni * 16 + cc;
            #pragma unroll
            for (int rr = 0; rr < 4; ++rr) {
                int rowg = m0 + wr * 64 + mi * 16 + cr + rr;
                float v = acc[mi][ni][rr];
                if (EPI == 0) v += extra[(rowg >> 8) * G4 + col];
                else          v += extra[col];
                C[(size_t)rowg * N + col] = v;
            }
        }
    }
}

// ---------------- poll helpers (sentinel = bit14 set) ----------------
__device__ __forceinline__ void poll16(const unsigned long long* row, int q,
        unsigned long long* ax, unsigned long long* ay) {
    for (;;) {
        unsigned long long bad = 0;
        #pragma unroll
        for (int kt = 0; kt < 16; ++kt) {
            ax[kt] = __hip_atomic_load(row + kt * 8 + q * 2,
                                       __ATOMIC_RELAXED, __HIP_MEMORY_SCOPE_AGENT);
            ay[kt] = __hip_atomic_load(row + kt * 8 + q * 2 + 1,
                                       __ATOMIC_RELAXED, __HIP_MEMORY_SCOPE_AGENT);
            bad |= (ax[kt] | ay[kt]) & SENTMASK;
        }
        if (!__any(bad != 0)) break;
    }
}

// dual-row poll: retries reload only the not-yet-valid row
__device__ __forceinline__ void poll16x2(const unsigned long long* rowA,
        const unsigned long long* rowB, int q,
        unsigned long long* ax, unsigned long long* ay,
        unsigned long long* bx, unsigned long long* by) {
    bool okA = false, okB = false;
    do {
        if (!okA) {
            unsigned long long bad = 0;
            #pragma unroll
            for (int kt = 0; kt < 16; ++kt) {
                ax[kt] = __hip_atomic_load(rowA + kt * 8 + q * 2,
                                           __ATOMIC_RELAXED, __HIP_MEMORY_SCOPE_AGENT);
                ay[kt] = __hip_atomic_load(rowA + kt * 8 + q * 2 + 1,
                                           __ATOMIC_RELAXED, __HIP_MEMORY_SCOPE_AGENT);
                bad |= (ax[kt] | ay[kt]) & SENTMASK;
            }
            okA = !__any(bad != 0);
        }
        if (!okB) {
            unsigned long long bad = 0;
            #pragma unroll
            for (int kt = 0; kt < 16; ++kt) {
                bx[kt] = __hip_atomic_load(rowB + kt * 8 + q * 2,
                                           __ATOMIC_RELAXED, __HIP_MEMORY_SCOPE_AGENT);
                by[kt] = __hip_atomic_load(rowB + kt * 8 + q * 2 + 1,
                                           __ATOMIC_RELAXED, __HIP_MEMORY_SCOPE_AGENT);
                bad |= (bx[kt] | by[kt]) & SENTMASK;
            }
            okB = !__any(bad != 0);
        }
    } while (!(okA && okB));
}

// ---------------- persistent dataflow recurrence (fence-free sentinel sync) ----------------
// 64 blocks x 64 threads. Blocks 0..31: layer 0, d-slice of 16; blocks 32..63: layer 1.
// Coalesced h-stores: 16x16 output tile staged in LDS, written as 64 x 8B agent stores.
__global__ __launch_bounds__(64) void k_recur(
        const float* __restrict__ Gx,
        const float* __restrict__ Whh0,
        const float* __restrict__ Wih1, const float* __restrict__ Whh1,
        const float* __restrict__ bih1, const float* __restrict__ bhh1,
        unsigned short* h0hist, unsigned short* outsb,
        const unsigned short* zbuf) {
    __shared__ __align__(16) unsigned short wfrag[4 * 32 * 512];   // 128 KB
    __shared__ __align__(8)  unsigned short houts[16 * 16];        // step output tile
    const int l = threadIdx.x;
    const int bid = blockIdx.x;
    const int role = bid >> 5;
    const int d0 = (bid & 31) * 16;
    const int r16 = l & 15;           // B-row within tile / A b-row / output col
    const int q = l >> 4;             // k-quadrant
    const int ksub = q * 8;
    const int b0 = q * 4;             // output b base (C/D: row=(lane>>4)*4+reg)
    const int sb = l >> 2, sseg = l & 3;   // store mapping: b-row, 8B segment

    // ---- stage weights into fragment-ordered LDS (once) ----
    const int nkt = role ? 32 : 16;
    for (int tile = 0; tile < 4; ++tile) {
        int j = tile * 512 + d0 + r16;            // gate=tile, dim=d0+r16
        for (int kt = 0; kt < nkt; ++kt) {
            const float* src;
            if (role == 0)    src = Whh0 + (size_t)j * DD + kt * 32 + ksub;
            else if (kt < 16) src = Wih1 + (size_t)j * DD + kt * 32 + ksub;
            else              src = Whh1 + (size_t)j * DD + (kt - 16) * 32 + ksub;
            float4 x = *(const float4*)src;
            float4 y = *(const float4*)(src + 4);
            bf16x8 w;
            w[0] = f2bf(x.x); w[1] = f2bf(x.y); w[2] = f2bf(x.z); w[3] = f2bf(x.w);
            w[4] = f2bf(y.x); w[5] = f2bf(y.y); w[6] = f2bf(y.z); w[7] = f2bf(y.w);
            *(bf16x8*)&wfrag[((tile * 32 + kt) * 64 + l) * 8] = w;
        }
    }
    __syncthreads();

    float cst[4] = {0.f, 0.f, 0.f, 0.f};
    unsigned long long ax[16], ay[16];

    if (role == 0) {
        for (int t = 0; t < TT; ++t) {
            // Gx prefetch (independent of h -> issues before the poll)
            float gx[4][4];
            #pragma unroll
            for (int ni = 0; ni < 4; ++ni)
                #pragma unroll
                for (int rr = 0; rr < 4; ++rr)
                    gx[ni][rr] = Gx[((size_t)(b0 + rr) * TT + t) * G4 + ni * 512 + d0 + r16];

            const unsigned long long* hrow =
                (const unsigned long long*)(h0hist + (size_t)t * (BB * DD) + r16 * DD);
            poll16(hrow, q, ax, ay);

            f32x4 acc[4];
            #pragma unroll
            for (int ni = 0; ni < 4; ++ni) acc[ni] = (f32x4)0.f;
            #pragma unroll
            for (int kt = 0; kt < 16; ++kt) {
                frag_u f; f.u[0] = ax[kt]; f.u[1] = ay[kt];
                #pragma unroll
                for (int ni = 0; ni < 4; ++ni) {
                    bf16x8 wf = *(const bf16x8*)&wfrag[((ni * 32 + kt) * 64 + l) * 8];
                    acc[ni] = __builtin_amdgcn_mfma_f32_16x16x32_bf16(f.v, wf, acc[ni], 0, 0, 0);
                }
            }
            #pragma unroll
            for (int rr = 0; rr < 4; ++rr) {
                float gi = acc[0][rr] + gx[0][rr], gf = acc[1][rr] + gx[1][rr];
                float gg = acc[2][rr] + gx[2][rr], go = acc[3][rr] + gx[3][rr];
                float cn = sigmoidf_(gf) * cst[rr] + sigmoidf_(gi) * tanhf(gg);
                float hn = sigmoidf_(go) * tanhf(cn);
                cst[rr] = cn;
                houts[(b0 + rr) * 16 + r16] = f2bf(hn);
            }
            __syncthreads();
            unsigned short* orow = h0hist + (size_t)(t + 1) * (BB * DD);
            unsigned long long w8 = *(const unsigned long long*)&houts[sb * 16 + sseg * 4];
            __hip_atomic_store((unsigned long long*)(orow + sb * DD + d0 + sseg * 4), w8,
                               __ATOMIC_RELAXED, __HIP_MEMORY_SCOPE_AGENT);
            __syncthreads();
        }
    } else {
        unsigned long long bx[16], by[16];
        float bin[4];
        #pragma unroll
        for (int ni = 0; ni < 4; ++ni)
            bin[ni] = bih1[ni * 512 + d0 + r16] + bhh1[ni * 512 + d0 + r16];
        for (int t = 0; t < TT; ++t) {
            const unsigned long long* xrow =
                (const unsigned long long*)(h0hist + (size_t)(t + 1) * (BB * DD) + r16 * DD);
            const unsigned long long* hrow = (t == 0)
                ? (const unsigned long long*)(zbuf + r16 * DD)
                : (const unsigned long long*)(outsb + ((size_t)r16 * TT + (t - 1)) * DD);
            poll16x2(xrow, hrow, q, ax, ay, bx, by);

            f32x4 acc[4];
            #pragma unroll
            for (int ni = 0; ni < 4; ++ni)
                acc[ni] = (f32x4){bin[ni], bin[ni], bin[ni], bin[ni]};
            #pragma unroll
            for (int kt = 0; kt < 16; ++kt) {
                frag_u f; f.u[0] = ax[kt]; f.u[1] = ay[kt];
                #pragma unroll
                for (int ni = 0; ni < 4; ++ni) {
                    bf16x8 wf = *(const bf16x8*)&wfrag[((ni * 32 + kt) * 64 + l) * 8];
                    acc[ni] = __builtin_amdgcn_mfma_f32_16x16x32_bf16(f.v, wf, acc[ni], 0, 0, 0);
                }
            }
            #pragma unroll
            for (int kt = 0; kt < 16; ++kt) {
                frag_u f; f.u[0] = bx[kt]; f.u[1] = by[kt];
                #pragma unroll
                for (int ni = 0; ni < 4; ++ni) {
                    bf16x8 wf = *(const bf16x8*)&wfrag[((ni * 32 + 16 + kt) * 64 + l) * 8];
                    acc[ni] = __builtin_amdgcn_mfma_f32_16x16x32_bf16(f.v, wf, acc[ni], 0, 0, 0);
                }
            }
            #pragma unroll
            for (int rr = 0; rr < 4; ++rr) {
                float gi = acc[0][rr], gf = acc[1][rr], gg = acc[2][rr], go = acc[3][rr];
                float cn = sigmoidf_(gf) * cst[rr] + sigmoidf_(gi) * tanhf(gg);
                float hn = sigmoidf_(go) * tanhf(cn);
                cst[rr] = cn;
                houts[(b0 + rr) * 16 + r16] = f2bf(hn);
            }
            __syncthreads();
            unsigned long long w8 = *(const unsigned long long*)&houts[sb * 16 + sseg * 4];
            __hip_atomic_store(
                (unsigned long long*)(outsb + ((size_t)sb * TT + t) * DD + d0 + sseg * 4), w8,
                __ATOMIC_RELAXED, __HIP_MEMORY_SCOPE_AGENT);
            __syncthreads();
        }
    }
}

extern "C" void kernel_launch(void* const* d_in, const int* in_sizes, int n_in,
                              void* d_out, int out_size, void* d_ws, size_t ws_size,
                              hipStream_t stream) {
    const int*   tok   = (const int*)  d_in[0];
    const float* enc   = (const float*)d_in[1];
    const float* embed = (const float*)d_in[2];
    const float* Wih0  = (const float*)d_in[3];
    const float* Whh0  = (const float*)d_in[4];
    const float* bih0  = (const float*)d_in[5];
    const float* bhh0  = (const float*)d_in[6];
    const float* Wih1  = (const float*)d_in[7];
    const float* Whh1  = (const float*)d_in[8];
    const float* bih1  = (const float*)d_in[9];
    const float* bhh1  = (const float*)d_in[10];
    const float* Wout  = (const float*)d_in[11];
    const float* bout  = (const float*)d_in[12];
    float* out = (float*)d_out;

    char* ws = (char*)d_ws;
    size_t off = 0;
    auto alloc = [&](size_t bytes) -> char* {
        char* p = ws + off; off += (bytes + 255) & ~(size_t)255; return p;
    };
    unsigned short* Xb     = (unsigned short*)alloc((size_t)BB * TT * DD * 2);
    unsigned short* Wih0xb = (unsigned short*)alloc((size_t)G4 * DD * 2);
    unsigned short* Woutb  = (unsigned short*)alloc((size_t)VV * DD * 2);
    float*          et     = (float*)alloc((size_t)BB * G4 * sizeof(float));
    float*          Gx     = (float*)alloc((size_t)BB * TT * G4 * sizeof(float));
    unsigned short* outsb  = (unsigned short*)alloc((size_t)BB * TT * DD * 2);
    unsigned short* h0hist = (unsigned short*)alloc((size_t)(TT + 1) * BB * DD * 2);
    unsigned short* zbuf   = (unsigned short*)alloc((size_t)BB * DD * 2);

    // sentinel init: slot 0 of h0hist + zbuf = zeros (valid), everything else 0xFF (invalid)
    hipMemsetAsync(h0hist, 0, (size_t)BB * DD * 2, stream);
    hipMemsetAsync(h0hist + (size_t)BB * DD, 0xFF, (size_t)TT * BB * DD * 2, stream);
    hipMemsetAsync(outsb, 0xFF, (size_t)BB * TT * DD * 2, stream);
    hipMemsetAsync(zbuf, 0, (size_t)BB * DD * 2, stream);

    k_gather<<<BB * TT, 256, 0, stream>>>(tok, embed, Xb);
    k_cvt<<<(VV * DD / 4 + 255) / 256, 256, 0, stream>>>(Wout, Woutb, VV * DD / 4);
    k_cvt_wih0x<<<(G4 * DD / 4) / 256, 256, 0, stream>>>(Wih0, Wih0xb);
    k_encterm<<<BB * 8, 256, 0, stream>>>(enc, Wih0, bih0, bhh0, et);

    dim3 g1(BB * TT / 128, G4 / 128);
    k_gemm_bt<0><<<g1, 256, 0, stream>>>(Xb, Wih0xb, Gx, et, BB * TT, G4, DD);

    k_recur<<<64, 64, 0, stream>>>(Gx, Whh0, Wih1, Whh1, bih1, bhh1,
                                   h0hist, outsb, zbuf);

    dim3 g2(BB * TT / 128, VV / 128);
    k_gemm_bt<1><<<g2, 256, 0, stream>>>(outsb, Woutb, out, bout, BB * TT, VV, DD);
}

// Round 8
// 1853.257 us; speedup vs baseline: 1.0627x; 1.0627x over previous
//
#include <hip/hip_runtime.h>
#include <hip/hip_bf16.h>
#include <math.h>

#define BB 16
#define TT 256
#define DD 512
#define EE 512
#define VV 32000
#define G4 2048   // 4*D

typedef __attribute__((ext_vector_type(4))) float f32x4;
typedef __attribute__((ext_vector_type(8))) short bf16x8;

union frag_u { unsigned long long u[2]; bf16x8 v; };

#define SENTMASK 0x4000400040004000ULL   // bit14 of each bf16: set in 0xFFFF sentinel, clear for |x|<2

__device__ __forceinline__ unsigned short f2bf(float x) {
    unsigned u = __float_as_uint(x);
    unsigned r = (u + 0x7FFFu + ((u >> 16) & 1u)) >> 16;
    return (unsigned short)r;
}

__device__ __forceinline__ float sigmoidf_(float x) { return 1.0f / (1.0f + expf(-x)); }

// ---------------- embedding gather -> bf16 (padding_idx=0 -> zero row) ----------------
__global__ __launch_bounds__(256) void k_gather(const int* __restrict__ tok,
        const float* __restrict__ embed, unsigned short* __restrict__ Xb) {
    int m = blockIdx.x;
    int tk = tok[m];
    const float* src = embed + (size_t)tk * DD;
    int i = threadIdx.x * 2;
    float vx = 0.f, vy = 0.f;
    if (tk != 0) { float2 v = *(const float2*)&src[i]; vx = v.x; vy = v.y; }
    ushort2 o; o.x = f2bf(vx); o.y = f2bf(vy);
    *(ushort2*)&Xb[(size_t)m * DD + i] = o;
}

// ---------------- generic fp32 -> bf16 convert (contiguous) ----------------
__global__ __launch_bounds__(256) void k_cvt(const float* __restrict__ in,
        unsigned short* __restrict__ out, int n4) {
    int i = blockIdx.x * 256 + threadIdx.x;
    if (i >= n4) return;
    float4 v = ((const float4*)in)[i];
    ushort4 o; o.x = f2bf(v.x); o.y = f2bf(v.y); o.z = f2bf(v.z); o.w = f2bf(v.w);
    ((ushort4*)out)[i] = o;
}

// ---------------- W_ih0[:, 0:512] -> packed bf16 [2048,512] ----------------
__global__ __launch_bounds__(256) void k_cvt_wih0x(const float* __restrict__ Wih0,
        unsigned short* __restrict__ out) {
    int i = blockIdx.x * 256 + threadIdx.x;
    int j = i >> 7;
    int k4 = (i & 127) << 2;
    float4 v = *(const float4*)&Wih0[(size_t)j * (EE + DD) + k4];
    ushort4 o; o.x = f2bf(v.x); o.y = f2bf(v.y); o.z = f2bf(v.z); o.w = f2bf(v.w);
    *(ushort4*)&out[(size_t)j * DD + k4] = o;
}

// ---------------- enc_term[b,j] = b_ih0[j]+b_hh0[j] + enc[b,:] . W_ih0[j, 512:1024] ----------------
__global__ __launch_bounds__(256) void k_encterm(const float* __restrict__ enc,
        const float* __restrict__ Wih0, const float* __restrict__ bih0,
        const float* __restrict__ bhh0, float* __restrict__ et) {
    int b = blockIdx.x >> 3, jc = blockIdx.x & 7;
    int tid = threadIdx.x, lane = tid & 63, w = tid >> 6;
    __shared__ float es[EE];
    if (tid < EE / 4) *(float4*)&es[tid * 4] = *(const float4*)&enc[b * EE + tid * 4];
    __syncthreads();
    float4 e0 = *(const float4*)&es[lane * 4];
    float4 e1 = *(const float4*)&es[256 + lane * 4];
    for (int o = 0; o < 64; ++o) {
        int j = jc * 256 + w * 64 + o;
        const float4* Wr = (const float4*)&Wih0[(size_t)j * (EE + DD) + DD];
        float4 w0 = Wr[lane], w1 = Wr[64 + lane];
        float s = w0.x*e0.x + w0.y*e0.y + w0.z*e0.z + w0.w*e0.w
                + w1.x*e1.x + w1.y*e1.y + w1.z*e1.z + w1.w*e1.w;
        #pragma unroll
        for (int off = 32; off; off >>= 1) s += __shfl_xor(s, off);
        if (lane == 0) et[b * G4 + j] = s + bih0[j] + bhh0[j];
    }
}

// ---------------- bf16 MFMA GEMM, C[M,N] = A[M,K] @ B[N,K]^T  (m97 structure) ----------------
template<int EPI>
__global__ __launch_bounds__(256) void k_gemm_bt(
        const unsigned short* __restrict__ A, const unsigned short* __restrict__ Bm,
        float* __restrict__ C, const float* __restrict__ extra,
        int M, int N, int K) {
    __shared__ __align__(16) unsigned short Alds[128 * 32];
    __shared__ __align__(16) unsigned short Blds[128 * 32];
    int tid = threadIdx.x, lane = tid & 63, w = tid >> 6;
    int wr = w >> 1, wc = w & 1;
    int m0 = blockIdx.x * 128, n0 = blockIdx.y * 128;
    f32x4 acc[4][4];
    #pragma unroll
    for (int i = 0; i < 4; i++)
        #pragma unroll
        for (int j = 0; j < 4; j++) acc[i][j] = (f32x4)0.f;

    const char* Abase = (const char*)A;
    const char* Bbase = (const char*)Bm;
    for (int ks = 0; ks < K; ks += 32) {
        #pragma unroll
        for (int c = 0; c < 2; ++c) {
            int f = (tid + c * 256) * 16;
            int row = f >> 6;
            int inb = f & 63;
            const char* gA = Abase + (((size_t)(m0 + row) * K + ks) * 2 + inb);
            __builtin_amdgcn_global_load_lds(
                (const __attribute__((address_space(1))) void*)gA,
                (__attribute__((address_space(3))) void*)((char*)Alds + f), 16, 0, 0);
            const char* gB = Bbase + (((size_t)(n0 + row) * K + ks) * 2 + inb);
            __builtin_amdgcn_global_load_lds(
                (const __attribute__((address_space(1))) void*)gB,
                (__attribute__((address_space(3))) void*)((char*)Blds + f), 16, 0, 0);
        }
        __syncthreads();
        bf16x8 af[4], bfr[4];
        int r = lane & 15, ko = (lane >> 4) * 8;
        #pragma unroll
        for (int mi = 0; mi < 4; ++mi)
            af[mi] = *(const bf16x8*)&Alds[(wr * 64 + mi * 16 + r) * 32 + ko];
        #pragma unroll
        for (int ni = 0; ni < 4; ++ni)
            bfr[ni] = *(const bf16x8*)&Blds[(wc * 64 + ni * 16 + r) * 32 + ko];
        #pragma unroll
        for (int mi = 0; mi < 4; ++mi)
            #pragma unroll
            for (int ni = 0; ni < 4; ++ni)
                acc[mi][ni] = __builtin_amdgcn_mfma_f32_16x16x32_bf16(af[mi], bfr[ni], acc[mi][ni], 0, 0, 0);
        __syncthreads();
    }
    int cr = (lane >> 4) * 4, cc = lane & 15;
    #pragma unroll
    for (int mi = 0; mi < 4; ++mi) {
        #pragma unroll
        for (int ni = 0; ni < 4; ++ni) {
            int col = n0 + wc * 64 + ni * 16 + cc;
            #pragma unroll
            for (int rr = 0; rr < 4; ++rr) {
                int rowg = m0 + wr * 64 + mi * 16 + cr + rr;
                float v = acc[mi][ni][rr];
                if (EPI == 0) v += extra[(rowg >> 8) * G4 + col];
                else          v += extra[col];
                C[(size_t)rowg * N + col] = v;
            }
        }
    }
}

// ---------------- sentinel payload poll (r3-proven): retry until bit14 clear everywhere ----------------
__device__ __forceinline__ void poll16(const unsigned long long* row, int q,
        unsigned long long* ax, unsigned long long* ay) {
    for (;;) {
        unsigned long long bad = 0;
        #pragma unroll
        for (int kt = 0; kt < 16; ++kt) {
            ax[kt] = __hip_atomic_load(row + kt * 8 + q * 2,
                                       __ATOMIC_RELAXED, __HIP_MEMORY_SCOPE_AGENT);
            ay[kt] = __hip_atomic_load(row + kt * 8 + q * 2 + 1,
                                       __ATOMIC_RELAXED, __HIP_MEMORY_SCOPE_AGENT);
            bad |= (ax[kt] | ay[kt]) & SENTMASK;
        }
        if (!__any(bad != 0)) break;
    }
}

// ---------------- persistent dataflow recurrence (sentinel sync, coalesced stores) ----------------
// 64 blocks x 64 threads (1 wave). Blocks 0..31: layer 0, d-slice of 16; 32..63: layer 1.
// Producer tile transpose in LDS: ALL accesses unsigned short (same TBAA type -> compiler
// keeps program order), explicit compiler fence between write/read phases, single-wave DS
// ops execute in order (no barrier needed). Then 64 x 8B relaxed agent stores (u64 built
// from four u16 reads). Sync is r3's sentinel protocol: payload self-validating, no
// cross-address ordering assumptions anywhere.
__global__ __launch_bounds__(64) void k_recur(
        const float* __restrict__ Gx,
        const float* __restrict__ Whh0,
        const float* __restrict__ Wih1, const float* __restrict__ Whh1,
        const float* __restrict__ bih1, const float* __restrict__ bhh1,
        unsigned short* h0hist, unsigned short* outsb,
        const unsigned short* zbuf) {
    __shared__ __align__(16) unsigned short wfrag[4 * 32 * 512];   // 128 KB
    __shared__ __align__(8)  unsigned short houts[16 * 16];        // transpose tile (u16 only)
    const int l = threadIdx.x;
    const int bid = blockIdx.x;
    const int role = bid >> 5;
    const int blk = bid & 31;
    const int d0 = blk * 16;
    const int r16 = l & 15;           // B-row within tile / A b-row
    const int q = l >> 4;             // k-quadrant
    const int ksub = q * 8;
    const int b0 = q * 4;             // output b base (C/D: row=(lane>>4)*4+reg)
    const int srow = l >> 2;          // coalesced-store: batch row
    const int sseg = l & 3;           // coalesced-store: 8B segment

    // ---- stage weights into fragment-ordered LDS (once) ----
    const int nkt = role ? 32 : 16;
    for (int tile = 0; tile < 4; ++tile) {
        int j = tile * 512 + d0 + r16;            // gate=tile, dim=d0+r16
        for (int kt = 0; kt < nkt; ++kt) {
            const float* src;
            if (role == 0)    src = Whh0 + (size_t)j * DD + kt * 32 + ksub;
            else if (kt < 16) src = Wih1 + (size_t)j * DD + kt * 32 + ksub;
            else              src = Whh1 + (size_t)j * DD + (kt - 16) * 32 + ksub;
            float4 x = *(const float4*)src;
            float4 y = *(const float4*)(src + 4);
            bf16x8 w;
            w[0] = f2bf(x.x); w[1] = f2bf(x.y); w[2] = f2bf(x.z); w[3] = f2bf(x.w);
            w[4] = f2bf(y.x); w[5] = f2bf(y.y); w[6] = f2bf(y.z); w[7] = f2bf(y.w);
            *(bf16x8*)&wfrag[((tile * 32 + kt) * 64 + l) * 8] = w;
        }
    }
    __syncthreads();

    float cst[4] = {0.f, 0.f, 0.f, 0.f};
    unsigned long long ax[16], ay[16];

    if (role == 0) {
        for (int t = 0; t < TT; ++t) {
            // Gx prefetch (independent of h -> overlaps the poll)
            float gx[4][4];
            #pragma unroll
            for (int ni = 0; ni < 4; ++ni)
                #pragma unroll
                for (int rr = 0; rr < 4; ++rr)
                    gx[ni][rr] = Gx[((size_t)(b0 + rr) * TT + t) * G4 + ni * 512 + d0 + r16];

            const unsigned long long* hrow =
                (const unsigned long long*)(h0hist + (size_t)t * (BB * DD) + r16 * DD);
            poll16(hrow, q, ax, ay);

            f32x4 acc[4];
            #pragma unroll
            for (int ni = 0; ni < 4; ++ni) acc[ni] = (f32x4)0.f;
            #pragma unroll
            for (int kt = 0; kt < 16; ++kt) {
                frag_u f; f.u[0] = ax[kt]; f.u[1] = ay[kt];
                #pragma unroll
                for (int ni = 0; ni < 4; ++ni) {
                    bf16x8 wf = *(const bf16x8*)&wfrag[((ni * 32 + kt) * 64 + l) * 8];
                    acc[ni] = __builtin_amdgcn_mfma_f32_16x16x32_bf16(f.v, wf, acc[ni], 0, 0, 0);
                }
            }
            #pragma unroll
            for (int rr = 0; rr < 4; ++rr) {
                float gi = acc[0][rr] + gx[0][rr], gf = acc[1][rr] + gx[1][rr];
                float gg = acc[2][rr] + gx[2][rr], go = acc[3][rr] + gx[3][rr];
                float cn = sigmoidf_(gf) * cst[rr] + sigmoidf_(gi) * tanhf(gg);
                float hn = sigmoidf_(go) * tanhf(cn);
                cst[rr] = cn;
                houts[(b0 + rr) * 16 + r16] = f2bf(hn);   // u16 store (same type as reads below)
            }
            asm volatile("" ::: "memory");   // compiler fence: no hoist of reads above stores
            {
                const unsigned short* hp = &houts[srow * 16 + sseg * 4];
                unsigned long long w8 =  (unsigned long long)hp[0]
                                      | ((unsigned long long)hp[1] << 16)
                                      | ((unsigned long long)hp[2] << 32)
                                      | ((unsigned long long)hp[3] << 48);
                __hip_atomic_store(
                    (unsigned long long*)(h0hist + (size_t)(t + 1) * (BB * DD) + srow * DD + d0 + sseg * 4),
                    w8, __ATOMIC_RELAXED, __HIP_MEMORY_SCOPE_AGENT);
            }
        }
    } else {
        float bin[4];
        #pragma unroll
        for (int ni = 0; ni < 4; ++ni)
            bin[ni] = bih1[ni * 512 + d0 + r16] + bhh1[ni * 512 + d0 + r16];
        for (int t = 0; t < TT; ++t) {
            // x = h0[t] (slot t+1): sentinel-read, x-half MFMAs first
            const unsigned long long* xrow =
                (const unsigned long long*)(h0hist + (size_t)(t + 1) * (BB * DD) + r16 * DD);
            poll16(xrow, q, ax, ay);

            f32x4 acc[4];
            #pragma unroll
            for (int ni = 0; ni < 4; ++ni)
                acc[ni] = (f32x4){bin[ni], bin[ni], bin[ni], bin[ni]};
            #pragma unroll
            for (int kt = 0; kt < 16; ++kt) {
                frag_u f; f.u[0] = ax[kt]; f.u[1] = ay[kt];
                #pragma unroll
                for (int ni = 0; ni < 4; ++ni) {
                    bf16x8 wf = *(const bf16x8*)&wfrag[((ni * 32 + kt) * 64 + l) * 8];
                    acc[ni] = __builtin_amdgcn_mfma_f32_16x16x32_bf16(f.v, wf, acc[ni], 0, 0, 0);
                }
            }
            // h1[t-1]: sentinel-read (producer peers), h-half MFMAs
            const unsigned long long* hrow = (t == 0)
                ? (const unsigned long long*)(zbuf + r16 * DD)
                : (const unsigned long long*)(outsb + ((size_t)r16 * TT + (t - 1)) * DD);
            poll16(hrow, q, ax, ay);
            #pragma unroll
            for (int kt = 0; kt < 16; ++kt) {
                frag_u f; f.u[0] = ax[kt]; f.u[1] = ay[kt];
                #pragma unroll
                for (int ni = 0; ni < 4; ++ni) {
                    bf16x8 wf = *(const bf16x8*)&wfrag[((ni * 32 + 16 + kt) * 64 + l) * 8];
                    acc[ni] = __builtin_amdgcn_mfma_f32_16x16x32_bf16(f.v, wf, acc[ni], 0, 0, 0);
                }
            }
            #pragma unroll
            for (int rr = 0; rr < 4; ++rr) {
                float gi = acc[0][rr], gf = acc[1][rr], gg = acc[2][rr], go = acc[3][rr];
                float cn = sigmoidf_(gf) * cst[rr] + sigmoidf_(gi) * tanhf(gg);
                float hn = sigmoidf_(go) * tanhf(cn);
                cst[rr] = cn;
                houts[(b0 + rr) * 16 + r16] = f2bf(hn);
            }
            asm volatile("" ::: "memory");
            {
                const unsigned short* hp = &houts[srow * 16 + sseg * 4];
                unsigned long long w8 =  (unsigned long long)hp[0]
                                      | ((unsigned long long)hp[1] << 16)
                                      | ((unsigned long long)hp[2] << 32)
                                      | ((unsigned long long)hp[3] << 48);
                __hip_atomic_store(
                    (unsigned long long*)(outsb + ((size_t)srow * TT + t) * DD + d0 + sseg * 4),
                    w8, __ATOMIC_RELAXED, __HIP_MEMORY_SCOPE_AGENT);
            }
        }
    }
}

extern "C" void kernel_launch(void* const* d_in, const int* in_sizes, int n_in,
                              void* d_out, int out_size, void* d_ws, size_t ws_size,
                              hipStream_t stream) {
    const int*   tok   = (const int*)  d_in[0];
    const float* enc   = (const float*)d_in[1];
    const float* embed = (const float*)d_in[2];
    const float* Wih0  = (const float*)d_in[3];
    const float* Whh0  = (const float*)d_in[4];
    const float* bih0  = (const float*)d_in[5];
    const float* bhh0  = (const float*)d_in[6];
    const float* Wih1  = (const float*)d_in[7];
    const float* Whh1  = (const float*)d_in[8];
    const float* bih1  = (const float*)d_in[9];
    const float* bhh1  = (const float*)d_in[10];
    const float* Wout  = (const float*)d_in[11];
    const float* bout  = (const float*)d_in[12];
    float* out = (float*)d_out;

    char* ws = (char*)d_ws;
    size_t off = 0;
    auto alloc = [&](size_t bytes) -> char* {
        char* p = ws + off; off += (bytes + 255) & ~(size_t)255; return p;
    };
    unsigned short* Xb     = (unsigned short*)alloc((size_t)BB * TT * DD * 2);
    unsigned short* Wih0xb = (unsigned short*)alloc((size_t)G4 * DD * 2);
    unsigned short* Woutb  = (unsigned short*)alloc((size_t)VV * DD * 2);
    float*          et     = (float*)alloc((size_t)BB * G4 * sizeof(float));
    float*          Gx     = (float*)alloc((size_t)BB * TT * G4 * sizeof(float));
    unsigned short* outsb  = (unsigned short*)alloc((size_t)BB * TT * DD * 2);
    unsigned short* h0hist = (unsigned short*)alloc((size_t)(TT + 1) * BB * DD * 2);
    unsigned short* zbuf   = (unsigned short*)alloc((size_t)BB * DD * 2);

    // sentinel init: slot 0 of h0hist + zbuf = zeros (valid), everything else 0xFF (invalid)
    hipMemsetAsync(h0hist, 0, (size_t)BB * DD * 2, stream);
    hipMemsetAsync(h0hist + (size_t)BB * DD, 0xFF, (size_t)TT * BB * DD * 2, stream);
    hipMemsetAsync(outsb, 0xFF, (size_t)BB * TT * DD * 2, stream);
    hipMemsetAsync(zbuf, 0, (size_t)BB * DD * 2, stream);

    k_gather<<<BB * TT, 256, 0, stream>>>(tok, embed, Xb);
    k_cvt<<<(VV * DD / 4 + 255) / 256, 256, 0, stream>>>(Wout, Woutb, VV * DD / 4);
    k_cvt_wih0x<<<(G4 * DD / 4) / 256, 256, 0, stream>>>(Wih0, Wih0xb);
    k_encterm<<<BB * 8, 256, 0, stream>>>(enc, Wih0, bih0, bhh0, et);

    dim3 g1(BB * TT / 128, G4 / 128);
    k_gemm_bt<0><<<g1, 256, 0, stream>>>(Xb, Wih0xb, Gx, et, BB * TT, G4, DD);

    k_recur<<<64, 64, 0, stream>>>(Gx, Whh0, Wih1, Whh1, bih1, bhh1,
                                   h0hist, outsb, zbuf);

    dim3 g2(BB * TT / 128, VV / 128);
    k_gemm_bt<1><<<g2, 256, 0, stream>>>(outsb, Woutb, out, bout, BB * TT, VV, DD);
}